// Round 18
// baseline (454.114 us; speedup 1.0000x reference)
//
#include <hip/hip_runtime.h>
#include <hip/hip_bf16.h>
#include <stdint.h>

typedef __attribute__((ext_vector_type(4)))  float f32x4;
typedef __attribute__((ext_vector_type(16))) float f32x16;
typedef __attribute__((ext_vector_type(8)))  short s16x8;
typedef __attribute__((ext_vector_type(4)))  short s16x4;

constexpr int I_SZ = 2048;
constexpr int O_SZ = 2048;
constexpr int T_SZ = 2048;
constexpr int B_MAX = 16;

// pre-tiled layout v2 (32x32x16 fragments): per (bz, tile128, kt16): 4KB block
// = 4 subtiles (32 rows) x 1KB; byte offset l*16 in a subtile holds lane l's
// fragment: row = l&31, k = kt16*16 + 4*(l>>5) + (j&3) + 8*(j>>2), j=0..7.
constexpr size_t XT_ELEMS = (size_t)B_MAX * T_SZ * I_SZ;
constexpr size_t WT_ELEMS = (size_t)B_MAX * I_SZ * O_SZ;
constexpr size_t WS_NEEDED = (XT_ELEMS + WT_ELEMS) * sizeof(short); // 256 MB

__device__ __forceinline__ short f2bf(float f) {
    __hip_bfloat16 h = __float2bfloat16(f);
    return *reinterpret_cast<short*>(&h);
}

__device__ __forceinline__ void gload_lds16(const void* g, void* l) {
    __builtin_amdgcn_global_load_lds(
        (const __attribute__((address_space(1))) unsigned int*)g,
        (__attribute__((address_space(3))) unsigned int*)l, 16, 0, 0);
}

// ---------------- conversion: x fp32 [B][T][I] -> pre-tiled v2 bf16 ----------------
__global__ __launch_bounds__(256) void convA(const float* __restrict__ x,
                                             short* __restrict__ xt) {
    const int c = blockIdx.x * 256 + threadIdx.x;   // 16B-chunk id (2^23 total)
    const int l   = c & 63;
    const int sub = (c >> 6) & 3;
    const int kt  = (c >> 8) & 127;
    const int rest = c >> 15;
    const int mt = rest & 15, bz = rest >> 4;
    const int m = mt * 128 + sub * 32 + (l & 31);
    const int kbase = kt * 16 + 4 * (l >> 5);
    const float* src = x + ((size_t)(bz * T_SZ + m)) * I_SZ + kbase;
    f32x4 a = *reinterpret_cast<const f32x4*>(src);
    f32x4 b = *reinterpret_cast<const f32x4*>(src + 8);
    s16x8 h = { f2bf(a[0]), f2bf(a[1]), f2bf(a[2]), f2bf(a[3]),
                f2bf(b[0]), f2bf(b[1]), f2bf(b[2]), f2bf(b[3]) };
    *reinterpret_cast<s16x8*>(xt + (size_t)c * 8) = h;
}

// ------- conversion: W fp32 [dom][I][O] gathered+transposed -> pre-tiled v2 ----
__global__ __launch_bounds__(256) void convB(const float* __restrict__ fcw,
                                             const int* __restrict__ dom_id,
                                             short* __restrict__ wt) {
    const int c = blockIdx.x * 256 + threadIdx.x;
    const int l   = c & 63;
    const int sub = (c >> 6) & 3;
    const int kt  = (c >> 8) & 127;
    const int rest = c >> 15;
    const int nt = rest & 15, bz = rest >> 4;
    const int n = nt * 128 + sub * 32 + (l & 31);
    const int kbase = kt * 16 + 4 * (l >> 5);
    const int dom = dom_id[bz];
    const float* src = fcw + (size_t)dom * ((size_t)I_SZ * O_SZ)
                           + (size_t)kbase * O_SZ + n;
    short h[8];
    #pragma unroll
    for (int j = 0; j < 4; ++j) {
        h[j]     = f2bf(src[(size_t)j * O_SZ]);
        h[4 + j] = f2bf(src[(size_t)(8 + j) * O_SZ]);
    }
    *reinterpret_cast<s16x8*>(wt + (size_t)c * 8) =
        *reinterpret_cast<s16x8*>(h);
}

// ---- bf16 GEMM, 128x256 tile, 4 waves, 2 blocks/CU, R16 schedule, 32x32x16 ----
// R17 null -> residual is the 16x16-shape matrix-pipe bound (2x64 MFMA x 19.4
// cyc/SIMD = 2484 cyc = 100% of measured iter). Swap to mfma_32x32x16_bf16:
// ceiling 2382 vs 2075 TF, MFMA count halved (32/K64/wave), same operand bytes.
// Schedule identical to R16 (all verified wins kept): ring-3 A-stage 2-ahead,
// vmcnt(4) per iter, bq same-register prefetch one phase-pair ahead.
// Per wave: 4 m-frags (32 rows) x 2 n-frags (32 cols); acc[4][2] f32x16 = 128 AGPR.
__global__ __launch_bounds__(256, 2) void gemm_128x256(
        const short* __restrict__ xt, const short* __restrict__ wt,
        const float* __restrict__ bw, const int* __restrict__ dom_id,
        float* __restrict__ out) {
    __shared__ short As[3][8192];   // ring-3 x 16KB (one K64 A-burst = 4 kt16 blocks)

    // bijective XCD swizzle: nwg = 2048 = 8 XCDs x 256
    const int bid = blockIdx.x;
    const int swz = (bid & 7) * 256 + (bid >> 3);
    const int bz = swz >> 7;
    const int mb = (swz >> 3) & 15;  // 128-row tile
    const int nb = swz & 7;          // 256-col tile

    const int t = threadIdx.x;
    const int wv = t >> 6, l = t & 63;
    const int lc = l & 31, lh = l >> 5;
    const int nt128 = nb * 2 + (wv >> 1);      // wave's 128-col B tile
    const int bsub  = 2 * (wv & 1);            // first of its two 32-col subtiles

    // per-tile128 pre-tiled panel = 128 kt16-blocks x 2048 shorts = 262144 shorts
    const short* Abase = xt + (size_t)(bz * 16 + mb) * 262144;
    const short* Bp = wt + (size_t)(bz * 16 + nt128) * 262144
                         + bsub * 512 + l * 8;

    auto stageA = [&](int buf, int T) {   // K64 burst = 4 kt16-blocks = 16KB
        #pragma unroll
        for (int r = 0; r < 4; ++r)
            gload_lds16(Abase + (size_t)(4 * T + r) * 2048 + t * 8,
                        &As[buf][r * 2048 + t * 8]);
    };

    f32x16 acc[4][2] = {};
    s16x8 bqS0[4], bqS1[4];   // [rr*2+g]: phase-pair register sets

    auto loadS0 = [&](int T) {            // kt16 steps 0,1 of iter T
        #pragma unroll
        for (int rr = 0; rr < 2; ++rr)
            #pragma unroll
            for (int g = 0; g < 2; ++g)
                bqS0[rr * 2 + g] = *reinterpret_cast<const s16x8*>(
                    Bp + (size_t)(4 * T + rr) * 2048 + g * 512);
    };
    auto loadS1 = [&](int T) {            // kt16 steps 2,3
        #pragma unroll
        for (int rr = 0; rr < 2; ++rr)
            #pragma unroll
            for (int g = 0; g < 2; ++g)
                bqS1[rr * 2 + g] = *reinterpret_cast<const s16x8*>(
                    Bp + (size_t)(4 * T + 2 + rr) * 2048 + g * 512);
    };

    auto phase = [&](int d, int r0, const s16x8* bq) {  // 2 kt16 steps, 16 MFMA
        #pragma unroll
        for (int rr = 0; rr < 2; ++rr) {
            const int r = r0 + rr;
            s16x8 af[4];
            #pragma unroll
            for (int s = 0; s < 4; ++s)
                af[s] = *reinterpret_cast<const s16x8*>(
                            &As[d][r * 2048 + s * 512 + l * 8]);
            __builtin_amdgcn_s_setprio(1);
            #pragma unroll
            for (int s = 0; s < 4; ++s)
                #pragma unroll
                for (int g = 0; g < 2; ++g)
                    acc[s][g] = __builtin_amdgcn_mfma_f32_32x32x16_bf16(
                                    af[s], bq[rr * 2 + g], acc[s][g], 0, 0, 0);
            __builtin_amdgcn_s_setprio(0);
        }
    };

    // prologue (R16 ledger): stage(0)[4] + S0(0)[4] + S1(0)[4] + stage(1)[4] = 16
    stageA(0, 0);
    loadS0(0);
    loadS1(0);
    stageA(1, 1);

    for (int T = 0; T < 32; ++T) {
        const int d = T % 3;
        const int nT = (T + 1 < 32) ? T + 1 : 31;   // tail clamp (same-value)

        // retire stage(T)+bq(T) [oldest 12]; keep stage(T+1) flying
        asm volatile("s_waitcnt vmcnt(4)" ::: "memory");
        asm volatile("s_barrier" ::: "memory");      // buf[d] globally ready

        phase(d, 0, bqS0);     // kt16 0,1
        loadS0(nT);            // S0 <- next iter (WAR held by compiler)

        phase(d, 2, bqS1);     // kt16 2,3
        loadS1(nT);
        stageA((T + 2) % 3, (T + 2 < 32) ? T + 2 : 31);   // 2-ahead, ring-3
    }

    asm volatile("s_waitcnt vmcnt(0)" ::: "memory");

    // epilogue: C/D 32x32 mapping (verified m74/m101): col = lane&31,
    // row = (reg&3) + 8*(reg>>2) + 4*(lane>>5)
    const int dom = dom_id[bz];
    const int col0 = nb * 256 + (wv >> 1) * 128 + (wv & 1) * 64;
    float bias[2];
    #pragma unroll
    for (int g = 0; g < 2; ++g)
        bias[g] = bw[dom * O_SZ + col0 + g * 32 + lc];

    const size_t obase = ((size_t)bz * T_SZ + mb * 128) * O_SZ + col0;
    #pragma unroll
    for (int s = 0; s < 4; ++s) {
        #pragma unroll
        for (int g = 0; g < 2; ++g) {
            #pragma unroll
            for (int r = 0; r < 16; ++r) {
                const int row = s * 32 + (r & 3) + 8 * (r >> 2) + 4 * lh;
                out[obase + (size_t)row * O_SZ + g * 32 + lc] =
                    acc[s][g][r] + bias[g];
            }
        }
    }
}

// =============== fallback (round-1 kernel) if workspace is too small ===============
constexpr int BM = 128, BN = 128, BK = 32;
constexpr int LDK = 40;
constexpr int NKT = I_SZ / BK;

__global__ __launch_bounds__(256) void dal_gemm(
    const float* __restrict__ x, const int* __restrict__ dom_id,
    const float* __restrict__ fcw, const float* __restrict__ bw,
    float* __restrict__ out)
{
    __shared__ short As[2][BM * LDK];
    __shared__ short Bs[2][BN * LDK];
    const int bz = blockIdx.z;
    const int m0 = blockIdx.y * BM, n0 = blockIdx.x * BN;
    const int dom = dom_id[bz];
    const float* Ag = x + ((size_t)bz * T_SZ + m0) * I_SZ;
    const float* Wg = fcw + (size_t)dom * ((size_t)I_SZ * O_SZ) + n0;
    const int t = threadIdx.x;
    const int am = t >> 3, ac = (t & 7) << 2;
    const int bk = (t >> 5) << 2, bn = (t & 31) << 2;
    const int wv = t >> 6, lane = t & 63;
    const int wr = (wv >> 1) << 6, wc = (wv & 1) << 6;
    const int hi = lane >> 4, lr = lane & 15;
    f32x4 acc[4][4] = {};
    f32x4 ra[4], rb[4];
    auto load_tile = [&](int kb) {
        #pragma unroll
        for (int p = 0; p < 4; ++p)
            ra[p] = *reinterpret_cast<const f32x4*>(Ag + (size_t)(am + 32 * p) * I_SZ + kb + ac);
        #pragma unroll
        for (int r = 0; r < 4; ++r)
            rb[r] = *reinterpret_cast<const f32x4*>(Wg + (size_t)(kb + bk + r) * O_SZ + bn);
    };
    auto store_tile = [&](int buf) {
        #pragma unroll
        for (int p = 0; p < 4; ++p) {
            s16x4 h = { f2bf(ra[p][0]), f2bf(ra[p][1]), f2bf(ra[p][2]), f2bf(ra[p][3]) };
            *reinterpret_cast<s16x4*>(&As[buf][(am + 32 * p) * LDK + ac]) = h;
        }
        #pragma unroll
        for (int i = 0; i < 4; ++i) {
            s16x4 h = { f2bf(rb[0][i]), f2bf(rb[1][i]), f2bf(rb[2][i]), f2bf(rb[3][i]) };
            *reinterpret_cast<s16x4*>(&Bs[buf][(bn + i) * LDK + bk]) = h;
        }
    };
    load_tile(0);
    store_tile(0);
    __syncthreads();
    for (int kt = 0; kt < NKT; ++kt) {
        const int cur = kt & 1;
        if (kt + 1 < NKT) load_tile((kt + 1) * BK);
        s16x8 af[4], bfr[4];
        #pragma unroll
        for (int im = 0; im < 4; ++im) {
            const short* p = &As[cur][(wr + im * 16 + lr) * LDK + 4 * hi];
            s16x4 lo = *reinterpret_cast<const s16x4*>(p);
            s16x4 hh = *reinterpret_cast<const s16x4*>(p + 16);
            af[im] = __builtin_shufflevector(lo, hh, 0, 1, 2, 3, 4, 5, 6, 7);
        }
        #pragma unroll
        for (int in = 0; in < 4; ++in) {
            const short* p = &Bs[cur][(wc + in * 16 + lr) * LDK + 4 * hi];
            s16x4 lo = *reinterpret_cast<const s16x4*>(p);
            s16x4 hh = *reinterpret_cast<const s16x4*>(p + 16);
            bfr[in] = __builtin_shufflevector(lo, hh, 0, 1, 2, 3, 4, 5, 6, 7);
        }
        #pragma unroll
        for (int im = 0; im < 4; ++im)
            #pragma unroll
            for (int in = 0; in < 4; ++in)
                acc[im][in] = __builtin_amdgcn_mfma_f32_16x16x32_bf16(
                                  af[im], bfr[in], acc[im][in], 0, 0, 0);
        if (kt + 1 < NKT) store_tile(cur ^ 1);
        __syncthreads();
    }
    float bias[4];
    #pragma unroll
    for (int in = 0; in < 4; ++in)
        bias[in] = bw[dom * O_SZ + n0 + wc + in * 16 + lr];
    const size_t obase = ((size_t)bz * T_SZ + m0) * O_SZ + n0;
    #pragma unroll
    for (int im = 0; im < 4; ++im) {
        #pragma unroll
        for (int r = 0; r < 4; ++r) {
            const int row = wr + im * 16 + hi * 4 + r;
            float* orow = out + obase + (size_t)row * O_SZ;
            #pragma unroll
            for (int in = 0; in < 4; ++in)
                orow[wc + in * 16 + lr] = acc[im][in][r] + bias[in];
        }
    }
}

extern "C" void kernel_launch(void* const* d_in, const int* in_sizes, int n_in,
                              void* d_out, int out_size, void* d_ws, size_t ws_size,
                              hipStream_t stream) {
    const float* x   = (const float*)d_in[0];
    const int*   dom = (const int*)d_in[1];
    const float* fcw = (const float*)d_in[2];
    const float* bw  = (const float*)d_in[3];
    float* out = (float*)d_out;
    const int B = in_sizes[1];   // 16

    if (ws_size >= WS_NEEDED && B == B_MAX) {
        short* xt = (short*)d_ws;
        short* wt = xt + XT_ELEMS;
        const int chunks = B * 16 * 128 * 4 * 64;          // 8,388,608
        convA<<<chunks / 256, 256, 0, stream>>>(x, xt);
        convB<<<chunks / 256, 256, 0, stream>>>(fcw, dom, wt);
        gemm_128x256<<<dim3(2048), dim3(256), 0, stream>>>(xt, wt, bw, dom, out);
    } else {
        dim3 grid(O_SZ / BN, T_SZ / BM, B);
        dal_gemm<<<grid, dim3(256), 0, stream>>>(x, dom, fcw, bw, out);
    }
}

// Round 19
// 389.455 us; speedup vs baseline: 1.1660x; 1.1660x over previous
//
#include <hip/hip_runtime.h>
#include <hip/hip_bf16.h>
#include <stdint.h>

typedef __attribute__((ext_vector_type(4))) float  f32x4;
typedef __attribute__((ext_vector_type(8))) short  s16x8;
typedef __attribute__((ext_vector_type(4))) short  s16x4;

constexpr int I_SZ = 2048;
constexpr int O_SZ = 2048;
constexpr int T_SZ = 2048;
constexpr int B_MAX = 16;

// pre-tiled layout: per (bz, tile128, ktile32): 8KB block = 8 subtiles x 1KB;
// within a subtile, byte offset l*16 holds the MFMA fragment of lane l:
// row = l&15, k = 4*(l>>4) + {0..3} and 16 + 4*(l>>4) + {0..3}
constexpr size_t XT_ELEMS = (size_t)B_MAX * T_SZ * I_SZ;
constexpr size_t WT_ELEMS = (size_t)B_MAX * I_SZ * O_SZ;
constexpr size_t WS_NEEDED = (XT_ELEMS + WT_ELEMS) * sizeof(short); // 256 MB

__device__ __forceinline__ short f2bf(float f) {
    __hip_bfloat16 h = __float2bfloat16(f);
    return *reinterpret_cast<short*>(&h);
}

__device__ __forceinline__ void gload_lds16(const void* g, void* l) {
    __builtin_amdgcn_global_load_lds(
        (const __attribute__((address_space(1))) unsigned int*)g,
        (__attribute__((address_space(3))) unsigned int*)l, 16, 0, 0);
}

// first occurrence of this bz's domain among bz'<=bz (16 scalar L2-hot loads)
__device__ __forceinline__ int first_bz(const int* __restrict__ dom_id, int bz) {
    const int d = dom_id[bz];
    for (int j = 0; j < bz; ++j)
        if (dom_id[j] == d) return j;
    return bz;
}

// ---------------- conversion: x fp32 [B][T][I] -> pre-tiled bf16 ----------------
__global__ __launch_bounds__(256) void convA(const float* __restrict__ x,
                                             short* __restrict__ xt) {
    const int c = blockIdx.x * 256 + threadIdx.x;
    const int l  = c & 63;
    const int mi = (c >> 6) & 7;
    const int kt = (c >> 9) & 63;
    const int rest = c >> 15;
    const int mt = rest & 15, bz = rest >> 4;
    const int lr = l & 15, hi = l >> 4;
    const int m = mt * 128 + mi * 16 + lr;
    const float* src = x + ((size_t)(bz * T_SZ + m)) * I_SZ + kt * 32 + 4 * hi;
    f32x4 a = *reinterpret_cast<const f32x4*>(src);
    f32x4 b = *reinterpret_cast<const f32x4*>(src + 16);
    s16x8 h = { f2bf(a[0]), f2bf(a[1]), f2bf(a[2]), f2bf(a[3]),
                f2bf(b[0]), f2bf(b[1]), f2bf(b[2]), f2bf(b[3]) };
    *reinterpret_cast<s16x8*>(xt + (size_t)c * 8) = h;
}

// ------- conversion: W fp32 [dom][I][O] gathered+transposed -> pre-tiled bf16 ----
// Domain-dedup: only the FIRST bz with a given domain converts its panel;
// duplicate slices exit immediately (GEMM reads the first-occurrence panel).
__global__ __launch_bounds__(256) void convB(const float* __restrict__ fcw,
                                             const int* __restrict__ dom_id,
                                             short* __restrict__ wt) {
    const int c = blockIdx.x * 256 + threadIdx.x;
    const int rest = c >> 15;
    const int nt = rest & 15, bz = rest >> 4;
    if (first_bz(dom_id, bz) != bz) return;          // duplicate panel: skip
    const int l  = c & 63;
    const int ni = (c >> 6) & 7;
    const int kt = (c >> 9) & 63;
    const int lr = l & 15, hi = l >> 4;
    const int n = nt * 128 + ni * 16 + lr;
    const int dom = dom_id[bz];
    const float* src = fcw + (size_t)dom * ((size_t)I_SZ * O_SZ)
                           + (size_t)(kt * 32 + 4 * hi) * O_SZ + n;
    short h[8];
    #pragma unroll
    for (int j = 0; j < 4; ++j) {
        h[j]     = f2bf(src[(size_t)j * O_SZ]);
        h[4 + j] = f2bf(src[(size_t)(16 + j) * O_SZ]);
    }
    *reinterpret_cast<s16x8*>(wt + (size_t)c * 8) =
        *reinterpret_cast<s16x8*>(h);
}

// ---- bf16 GEMM, 128x256 tile, 4 waves, 2 blocks/CU, ring-3, B prefetch-ahead ----
// Verified best structure (R16 = 265us GEMM, MfmaUtil 47%): 2 blocks/CU
// (R14 lever), ring-3 A-stage 2-ahead with vmcnt(4) (R15 lever), bq
// same-register prefetch one iter ahead (R16 lever). Delivery audit: 96KB/
// CU-iter in ~4969 cyc = 19.3 B/cyc/CU = the empirical per-CU delivery wall.
// Only change this round: B panel base uses first_bz(dom) for dedup/L2 reuse.
__global__ __launch_bounds__(256, 2) void gemm_128x256(
        const short* __restrict__ xt, const short* __restrict__ wt,
        const float* __restrict__ bw, const int* __restrict__ dom_id,
        float* __restrict__ out) {
    __shared__ short As[3][8192];   // ring-3 x 16KB (one K64 A-burst, pre-tiled)

    // bijective XCD swizzle: nwg = 2048 = 8 XCDs x 256
    const int bid = blockIdx.x;
    const int swz = (bid & 7) * 256 + (bid >> 3);
    const int bz = swz >> 7;         // 128 blocks per bz
    const int mb = (swz >> 3) & 15;  // 128-row tile index (A panel shared by 8 nb)
    const int nb = swz & 7;          // 256-col tile index
    const int fb = first_bz(dom_id, bz);   // dedup'd B panel slice

    const int t = threadIdx.x;
    const int wv = t >> 6, l = t & 63;
    const int lr = l & 15, hi = l >> 4;
    const int nti  = wv >> 1;        // which 128-col sub-tile of the 256 N-tile
    const int bsub = (wv & 1) * 4;   // which 4-subtile half within it

    // A: kt innermost in the pre-tiled layout -> a K64 burst is 16KB contiguous
    const short* Abase = xt + (size_t)(bz * 16 + mb) * 64 * 4096;
    // per-lane B fragment base (this wave's exclusive column quarter)
    const short* Bp = wt + (size_t)((fb * 16 + nb * 2 + nti) * 64) * 4096
                         + bsub * 512 + l * 8;

    auto stageA = [&](int buf, int T) {
        #pragma unroll
        for (int r = 0; r < 4; ++r)   // 4 x 4KB rounds (256 thr x 16B), lane-linear
            gload_lds16(Abase + (size_t)(2 * T) * 4096 + r * 2048 + t * 8,
                        &As[buf][r * 2048 + t * 8]);
    };

    f32x4 acc[8][4] = {};
    s16x8 bq0[4], bq1[4];

    auto loadB0 = [&](int T) {
        const short* b0 = Bp + (size_t)(2 * T) * 4096;
        #pragma unroll
        for (int g = 0; g < 4; ++g)
            bq0[g] = *reinterpret_cast<const s16x8*>(b0 + g * 512);
    };
    auto loadB1 = [&](int T) {
        const short* b1 = Bp + (size_t)(2 * T) * 4096 + 4096;
        #pragma unroll
        for (int g = 0; g < 4; ++g)
            bq1[g] = *reinterpret_cast<const s16x8*>(b1 + g * 512);
    };

    // prologue: stage(0), bq(0), stage(1) -> outstanding 16
    stageA(0, 0);
    loadB0(0);
    loadB1(0);
    stageA(1, 1);

    for (int T = 0; T < 32; ++T) {
        const int d = T % 3;
        const int nT = (T + 1 < 32) ? T + 1 : 31;   // tail clamp (same-value)

        // retire stage(T) + bq(T) [oldest 12]; keep stage(T+1) flying
        asm volatile("s_waitcnt vmcnt(4)" ::: "memory");
        asm volatile("s_barrier" ::: "memory");      // buf[d] globally ready

        // ks = 0 (consumes bq0)
        s16x8 af[8];
        #pragma unroll
        for (int f = 0; f < 8; ++f)
            af[f] = *reinterpret_cast<const s16x8*>(&As[d][f * 512 + l * 8]);
        __builtin_amdgcn_s_setprio(1);
        #pragma unroll
        for (int f = 0; f < 8; ++f)
            #pragma unroll
            for (int g = 0; g < 4; ++g)
                acc[f][g] = __builtin_amdgcn_mfma_f32_16x16x32_bf16(
                                af[f], bq0[g], acc[f][g], 0, 0, 0);
        __builtin_amdgcn_s_setprio(0);

        // prefetch bq0(T+1) into the same regs (WAR vs ks0 MFMAs: compiler-held)
        loadB0(nT);

        // ks = 1 (consumes bq1)
        #pragma unroll
        for (int f = 0; f < 8; ++f)
            af[f] = *reinterpret_cast<const s16x8*>(&As[d][4096 + f * 512 + l * 8]);
        __builtin_amdgcn_s_setprio(1);
        #pragma unroll
        for (int f = 0; f < 8; ++f)
            #pragma unroll
            for (int g = 0; g < 4; ++g)
                acc[f][g] = __builtin_amdgcn_mfma_f32_16x16x32_bf16(
                                af[f], bq1[g], acc[f][g], 0, 0, 0);
        __builtin_amdgcn_s_setprio(0);

        // prefetch bq1(T+1); stage A for T+2 (2-ahead, ring-3)
        loadB1(nT);
        stageA((T + 2) % 3, (T + 2 < 32) ? T + 2 : 31);
    }

    asm volatile("s_waitcnt vmcnt(0)" ::: "memory");   // retire tail issues

    // epilogue: wave tile = rows mb*128..+128, cols nb*256 + wv*64 .. +64
    const int dom = dom_id[bz];
    const int col0 = nb * 256 + wv * 64;
    float bias[4];
    #pragma unroll
    for (int g = 0; g < 4; ++g)
        bias[g] = bw[dom * O_SZ + col0 + g * 16 + lr];

    const size_t obase = ((size_t)bz * T_SZ + mb * 128) * O_SZ + col0;
    #pragma unroll
    for (int f = 0; f < 8; ++f) {
        #pragma unroll
        for (int r = 0; r < 4; ++r) {
            const int row = f * 16 + hi * 4 + r;
            float* orow = out + obase + (size_t)row * O_SZ;
            #pragma unroll
            for (int g = 0; g < 4; ++g)
                orow[g * 16 + lr] = acc[f][g][r] + bias[g];
        }
    }
}

// =============== fallback (round-1 kernel) if workspace is too small ===============
constexpr int BM = 128, BN = 128, BK = 32;
constexpr int LDK = 40;
constexpr int NKT = I_SZ / BK;

__global__ __launch_bounds__(256) void dal_gemm(
    const float* __restrict__ x, const int* __restrict__ dom_id,
    const float* __restrict__ fcw, const float* __restrict__ bw,
    float* __restrict__ out)
{
    __shared__ short As[2][BM * LDK];
    __shared__ short Bs[2][BN * LDK];
    const int bz = blockIdx.z;
    const int m0 = blockIdx.y * BM, n0 = blockIdx.x * BN;
    const int dom = dom_id[bz];
    const float* Ag = x + ((size_t)bz * T_SZ + m0) * I_SZ;
    const float* Wg = fcw + (size_t)dom * ((size_t)I_SZ * O_SZ) + n0;
    const int t = threadIdx.x;
    const int am = t >> 3, ac = (t & 7) << 2;
    const int bk = (t >> 5) << 2, bn = (t & 31) << 2;
    const int wv = t >> 6, lane = t & 63;
    const int wr = (wv >> 1) << 6, wc = (wv & 1) << 6;
    const int hi = lane >> 4, lr = lane & 15;
    f32x4 acc[4][4] = {};
    f32x4 ra[4], rb[4];
    auto load_tile = [&](int kb) {
        #pragma unroll
        for (int p = 0; p < 4; ++p)
            ra[p] = *reinterpret_cast<const f32x4*>(Ag + (size_t)(am + 32 * p) * I_SZ + kb + ac);
        #pragma unroll
        for (int r = 0; r < 4; ++r)
            rb[r] = *reinterpret_cast<const f32x4*>(Wg + (size_t)(kb + bk + r) * O_SZ + bn);
    };
    auto store_tile = [&](int buf) {
        #pragma unroll
        for (int p = 0; p < 4; ++p) {
            s16x4 h = { f2bf(ra[p][0]), f2bf(ra[p][1]), f2bf(ra[p][2]), f2bf(ra[p][3]) };
            *reinterpret_cast<s16x4*>(&As[buf][(am + 32 * p) * LDK + ac]) = h;
        }
        #pragma unroll
        for (int i = 0; i < 4; ++i) {
            s16x4 h = { f2bf(rb[0][i]), f2bf(rb[1][i]), f2bf(rb[2][i]), f2bf(rb[3][i]) };
            *reinterpret_cast<s16x4*>(&Bs[buf][(bn + i) * LDK + bk]) = h;
        }
    };
    load_tile(0);
    store_tile(0);
    __syncthreads();
    for (int kt = 0; kt < NKT; ++kt) {
        const int cur = kt & 1;
        if (kt + 1 < NKT) load_tile((kt + 1) * BK);
        s16x8 af[4], bfr[4];
        #pragma unroll
        for (int im = 0; im < 4; ++im) {
            const short* p = &As[cur][(wr + im * 16 + lr) * LDK + 4 * hi];
            s16x4 lo = *reinterpret_cast<const s16x4*>(p);
            s16x4 hh = *reinterpret_cast<const s16x4*>(p + 16);
            af[im] = __builtin_shufflevector(lo, hh, 0, 1, 2, 3, 4, 5, 6, 7);
        }
        #pragma unroll
        for (int in = 0; in < 4; ++in) {
            const short* p = &Bs[cur][(wc + in * 16 + lr) * LDK + 4 * hi];
            s16x4 lo = *reinterpret_cast<const s16x4*>(p);
            s16x4 hh = *reinterpret_cast<const s16x4*>(p + 16);
            bfr[in] = __builtin_shufflevector(lo, hh, 0, 1, 2, 3, 4, 5, 6, 7);
        }
        #pragma unroll
        for (int im = 0; im < 4; ++im)
            #pragma unroll
            for (int in = 0; in < 4; ++in)
                acc[im][in] = __builtin_amdgcn_mfma_f32_16x16x32_bf16(
                                  af[im], bfr[in], acc[im][in], 0, 0, 0);
        if (kt + 1 < NKT) store_tile(cur ^ 1);
        __syncthreads();
    }
    float bias[4];
    #pragma unroll
    for (int in = 0; in < 4; ++in)
        bias[in] = bw[dom * O_SZ + n0 + wc + in * 16 + lr];
    const size_t obase = ((size_t)bz * T_SZ + m0) * O_SZ + n0;
    #pragma unroll
    for (int im = 0; im < 4; ++im) {
        #pragma unroll
        for (int r = 0; r < 4; ++r) {
            const int row = wr + im * 16 + hi * 4 + r;
            float* orow = out + obase + (size_t)row * O_SZ;
            #pragma unroll
            for (int in = 0; in < 4; ++in)
                orow[wc + in * 16 + lr] = acc[im][in][r] + bias[in];
        }
    }
}

extern "C" void kernel_launch(void* const* d_in, const int* in_sizes, int n_in,
                              void* d_out, int out_size, void* d_ws, size_t ws_size,
                              hipStream_t stream) {
    const float* x   = (const float*)d_in[0];
    const int*   dom = (const int*)d_in[1];
    const float* fcw = (const float*)d_in[2];
    const float* bw  = (const float*)d_in[3];
    float* out = (float*)d_out;
    const int B = in_sizes[1];   // 16

    if (ws_size >= WS_NEEDED && B == B_MAX) {
        short* xt = (short*)d_ws;
        short* wt = xt + XT_ELEMS;
        const int chunks = B * 16 * 64 * 512;
        convA<<<chunks / 256, 256, 0, stream>>>(x, xt);
        convB<<<chunks / 256, 256, 0, stream>>>(fcw, dom, wt);
        gemm_128x256<<<dim3(2048), dim3(256), 0, stream>>>(xt, wt, bw, dom, out);
    } else {
        dim3 grid(O_SZ / BN, T_SZ / BM, B);
        dal_gemm<<<grid, dim3(256), 0, stream>>>(x, dom, fcw, bw, out);
    }
}